// Round 1
// baseline (2984.151 us; speedup 1.0000x reference)
//
#include <hip/hip_runtime.h>
#include <math.h>

#define NB   8
#define NC   256
#define NH   80
#define NW   80
#define NHW  6400
#define NG   32
#define CPG  8           // channels per group
#define GN_EPS 1e-5f
#define CI_CHUNK 4

// ---------------- zero the stats scratch ----------------
__global__ void zero_stats_kernel(float* stats) {
    // 2048 floats total
    int i = threadIdx.x;
    #pragma unroll
    for (int k = 0; k < 8; k++) stats[i + k * 256] = 0.0f;
}

// ---------------- spatial gate: g = clip(tanh(1x1conv(x) + b), 0, inf) ----------------
__global__ __launch_bounds__(256) void gate_kernel(
    const float* __restrict__ x, const float* __restrict__ gw,
    const float* __restrict__ gb, float* __restrict__ gate)
{
    int i = blockIdx.x * 256 + threadIdx.x;   // [0, NB*NHW)
    int b = i / NHW;
    int p = i - b * NHW;
    const float* xp = x + (size_t)b * NC * NHW + p;
    float g = 0.0f;
    #pragma unroll 4
    for (int c = 0; c < NC; c++) g = fmaf(xp[(size_t)c * NHW], gw[c], g);
    g = tanhf(g + gb[0]);
    gate[i] = fmaxf(g, 0.0f);
}

// ---------------- 3x3 conv, optional fused GN+ReLU on the INPUT, stats on the OUTPUT ----
// Block: one (batch, 32-output-channel tile, row h). 256 threads:
//   co_sub = tid>>3 (32 channels), px0 = (tid&7)*10 (10 pixels each).
__global__ __launch_bounds__(256) void conv3x3_kernel(
    const float* __restrict__ in, const float* __restrict__ wgt,
    float* __restrict__ out,
    const float* __restrict__ mu, const float* __restrict__ rsig,
    const float* __restrict__ gamma, const float* __restrict__ beta,
    int apply_gn,
    float* __restrict__ stat_sum, float* __restrict__ stat_sq)
{
    __shared__ float ldsIn[CI_CHUNK][3][84];   // 82 used (+pad)
    __shared__ float ldsW[CI_CHUNK][32][9];

    int blk = blockIdx.x;
    int b   = blk / (8 * 80);
    int rem = blk - b * (8 * 80);
    int cot = rem / 80;
    int h   = rem - cot * 80;
    int co0 = cot * 32;

    int tid    = threadIdx.x;
    int co_sub = tid >> 3;
    int px0    = (tid & 7) * 10;

    float acc[10];
    #pragma unroll
    for (int j = 0; j < 10; j++) acc[j] = 0.0f;

    for (int ci0 = 0; ci0 < NC; ci0 += CI_CHUNK) {
        __syncthreads();
        // stage input rows (with halo, zero-padded): CI_CHUNK*3*82 = 984 elems
        for (int e = tid; e < CI_CHUNK * 3 * 82; e += 256) {
            int cc  = e / (3 * 82);
            int r2  = e - cc * (3 * 82);
            int rr  = r2 / 82;
            int wi  = r2 - rr * 82;
            int row = h + rr - 1;
            int ws  = wi - 1;
            float v = 0.0f;
            if ((unsigned)row < 80u && (unsigned)ws < 80u) {
                int ci = ci0 + cc;
                v = in[((size_t)(b * NC + ci) * NH + row) * NW + ws];
                if (apply_gn) {
                    int idx = b * NG + (ci >> 3);
                    v = (v - mu[idx]) * rsig[idx] * gamma[ci] + beta[ci];
                    v = fmaxf(v, 0.0f);
                }
            }
            ldsIn[cc][rr][wi] = v;
        }
        // stage weights: CI_CHUNK*32*9 = 1152 elems
        for (int e = tid; e < CI_CHUNK * 32 * 9; e += 256) {
            int cc = e / (32 * 9);
            int r2 = e - cc * (32 * 9);
            int cs = r2 / 9;
            int kk = r2 - cs * 9;
            ldsW[cc][cs][kk] = wgt[((size_t)(co0 + cs) * NC + (ci0 + cc)) * 9 + kk];
        }
        __syncthreads();

        for (int cc = 0; cc < CI_CHUNK; cc++) {
            float wr[9];
            #pragma unroll
            for (int k = 0; k < 9; k++) wr[k] = ldsW[cc][co_sub][k];
            float iv[3][12];
            #pragma unroll
            for (int r = 0; r < 3; r++)
                #pragma unroll
                for (int t = 0; t < 12; t++) iv[r][t] = ldsIn[cc][r][px0 + t];
            #pragma unroll
            for (int j = 0; j < 10; j++)
                #pragma unroll
                for (int r = 0; r < 3; r++)
                    #pragma unroll
                    for (int s = 0; s < 3; s++)
                        acc[j] = fmaf(wr[r * 3 + s], iv[r][j + s], acc[j]);
        }
    }

    // write outputs + accumulate group stats
    int co = co0 + co_sub;
    size_t obase = ((size_t)(b * NC + co) * NH + h) * NW + px0;
    float lsum = 0.0f, lsq = 0.0f;
    #pragma unroll
    for (int j = 0; j < 10; j++) {
        float v = acc[j];
        out[obase + j] = v;
        lsum += v;
        lsq  = fmaf(v, v, lsq);
    }
    // each wave (64 lanes) covers exactly one group's 8 channels x 80 px
    #pragma unroll
    for (int off = 32; off > 0; off >>= 1) {
        lsum += __shfl_down(lsum, off, 64);
        lsq  += __shfl_down(lsq,  off, 64);
    }
    if ((tid & 63) == 0) {
        int idx = b * NG + (co >> 3);
        atomicAdd(&stat_sum[idx], lsum);
        atomicAdd(&stat_sq[idx],  lsq);
    }
}

// ---------------- finalize group stats: mu, rsigma per (b, g) ----------------
__global__ void statfin_kernel(const float* __restrict__ s,
                               const float* __restrict__ sq,
                               float* __restrict__ mu, float* __restrict__ rs)
{
    int i = threadIdx.x;   // 256 = NB*NG
    const float cnt = (float)(CPG * NHW);
    float m = s[i] / cnt;
    float v = sq[i] / cnt - m * m;
    mu[i] = m;
    rs[i] = rsqrtf(v + GN_EPS);
}

// ---------------- epilogue: out = relu(gn2(y2) * gate + x), in place on d_out ------
__global__ __launch_bounds__(256) void final_kernel(
    float* io,                                   // y2 in, result out (same buffer)
    const float* __restrict__ x, const float* __restrict__ gate,
    const float* __restrict__ mu, const float* __restrict__ rs,
    const float* __restrict__ gamma, const float* __restrict__ beta)
{
    size_t n = ((size_t)blockIdx.x * 256 + threadIdx.x) * 4;
    int b = (int)(n / ((size_t)NC * NHW));
    int c = (int)((n / NHW) & (NC - 1));
    int p = (int)(n % NHW);
    int idx = b * NG + (c >> 3);
    float m = mu[idx], r = rs[idx];
    float sc = r * gamma[c];
    float sh = beta[c] - m * sc;
    float4 y  = *(const float4*)(io + n);
    float4 xv = *(const float4*)(x + n);
    const float* gp = gate + b * NHW + p;
    float4 o;
    o.x = fmaxf(fmaf(fmaf(y.x, sc, sh), gp[0], xv.x), 0.0f);
    o.y = fmaxf(fmaf(fmaf(y.y, sc, sh), gp[1], xv.y), 0.0f);
    o.z = fmaxf(fmaf(fmaf(y.z, sc, sh), gp[2], xv.z), 0.0f);
    o.w = fmaxf(fmaf(fmaf(y.w, sc, sh), gp[3], xv.w), 0.0f);
    *(float4*)(io + n) = o;
}

extern "C" void kernel_launch(void* const* d_in, const int* in_sizes, int n_in,
                              void* d_out, int out_size, void* d_ws, size_t ws_size,
                              hipStream_t stream)
{
    const float* x     = (const float*)d_in[0];
    const float* w1    = (const float*)d_in[1];
    const float* gn1_w = (const float*)d_in[2];
    const float* gn1_b = (const float*)d_in[3];
    const float* w2    = (const float*)d_in[4];
    const float* gn2_w = (const float*)d_in[5];
    const float* gn2_b = (const float*)d_in[6];
    const float* gw    = (const float*)d_in[7];
    const float* gb    = (const float*)d_in[8];
    float* out = (float*)d_out;

    // workspace layout (floats)
    float* ws    = (float*)d_ws;
    float* y1    = ws;                                  // 13,107,200
    float* gate  = ws + (size_t)NB * NC * NHW;          // 51,200
    float* stats = gate + (size_t)NB * NHW;             // 2048 floats
    float* s1_sum = stats;          // 256
    float* s1_sq  = stats + 256;
    float* mu1    = stats + 512;
    float* rs1    = stats + 768;
    float* s2_sum = stats + 1024;
    float* s2_sq  = stats + 1280;
    float* mu2    = stats + 1536;
    float* rs2    = stats + 1792;

    zero_stats_kernel<<<1, 256, 0, stream>>>(stats);

    gate_kernel<<<(NB * NHW) / 256, 256, 0, stream>>>(x, gw, gb, gate);

    // conv1: x -> y1 (raw), stats -> s1
    conv3x3_kernel<<<NB * 8 * 80, 256, 0, stream>>>(
        x, w1, y1, nullptr, nullptr, nullptr, nullptr, 0, s1_sum, s1_sq);

    statfin_kernel<<<1, 256, 0, stream>>>(s1_sum, s1_sq, mu1, rs1);

    // conv2: relu(gn1(y1)) -> y2 (stored raw in d_out), stats -> s2
    conv3x3_kernel<<<NB * 8 * 80, 256, 0, stream>>>(
        y1, w2, out, mu1, rs1, gn1_w, gn1_b, 1, s2_sum, s2_sq);

    statfin_kernel<<<1, 256, 0, stream>>>(s2_sum, s2_sq, mu2, rs2);

    // epilogue: out = relu(gn2(y2) * gate + x)
    final_kernel<<<(NB * NC * NHW) / (256 * 4), 256, 0, stream>>>(
        out, x, gate, mu2, rs2, gn2_w, gn2_b);
}

// Round 2
// 372.316 us; speedup vs baseline: 8.0151x; 8.0151x over previous
//
#include <hip/hip_runtime.h>
#include <math.h>

#define NB   8
#define NC   256
#define NH   80
#define NW   80
#define NHW  6400
#define GN_EPS 1e-5f

typedef __bf16 bf16;
typedef bf16 bf16x2 __attribute__((ext_vector_type(2)));
typedef bf16 bf16x4 __attribute__((ext_vector_type(4)));
typedef bf16 bf16x8 __attribute__((ext_vector_type(8)));
typedef float f32x4 __attribute__((ext_vector_type(4)));

// ---------------- zero xp scratch (in d_out): 27,541,504 B = 1,721,344 uint4 ----
__global__ __launch_bounds__(256) void zero_xp_kernel(uint4* p) {
    p[(size_t)blockIdx.x * 256 + threadIdx.x] = make_uint4(0u, 0u, 0u, 0u);
}

__global__ void zero_stats_kernel(float* stats) {
    int i = threadIdx.x;
    #pragma unroll
    for (int k = 0; k < 4; k++) stats[i + k * 256] = 0.0f;  // s1,s1q,s2,s2q
}

// ---------------- repack weights: w[co][ci][3][3] f32 -> wA[chunk][tap][qq][co][c8] bf16
__global__ __launch_bounds__(256) void repack_w_kernel(
    const float* __restrict__ w, bf16* __restrict__ wA)
{
    int idx = blockIdx.x * 256 + threadIdx.x;            // 0..589823
    int c8 = idx & 7;
    int co = (idx >> 3) & 255;
    int qq = (idx >> 11) & 3;
    int tc = idx >> 13;                                   // 0..71
    int tap = tc % 9, chunk = tc / 9;
    int ci = chunk * 32 + qq * 8 + c8;
    wA[idx] = (bf16)w[(size_t)(co * 256 + ci) * 9 + tap];
}

// ---------------- spatial gate ----------------
__global__ __launch_bounds__(256) void gate_kernel(
    const float* __restrict__ x, const float* __restrict__ gw,
    const float* __restrict__ gb, float* __restrict__ gate)
{
    __shared__ float part[4][64];
    __shared__ float gwl[256];
    int b = blockIdx.x / 100, tile = blockIdx.x % 100;
    gwl[threadIdx.x] = gw[threadIdx.x];
    __syncthreads();
    int seg = threadIdx.x >> 6, ln = threadIdx.x & 63;
    int px = tile * 64 + ln;
    const float* xp = x + (size_t)(b * NC + seg * 64) * NHW + px;
    float s = 0.0f;
    #pragma unroll 8
    for (int i = 0; i < 64; i++) s = fmaf(xp[(size_t)i * NHW], gwl[seg * 64 + i], s);
    part[seg][ln] = s;
    __syncthreads();
    if (threadIdx.x < 64) {
        float t = part[0][threadIdx.x] + part[1][threadIdx.x] +
                  part[2][threadIdx.x] + part[3][threadIdx.x] + gb[0];
        gate[b * NHW + tile * 64 + threadIdx.x] = fmaxf(tanhf(t), 0.0f);
    }
}

// ---------------- prep1: x NCHW f32 -> xp[b][cib][82][82][8] bf16 (interior) ----
__global__ __launch_bounds__(256) void prep1_kernel(
    const float* __restrict__ x, bf16* __restrict__ xp)
{
    __shared__ float tile[8 * 84];
    int bid = blockIdx.x;
    int row = bid % 80;
    int cib = (bid / 80) & 31;
    int b   = bid / 2560;
    for (int e = threadIdx.x; e < 640; e += 256) {
        int c8 = e / 80, col = e - c8 * 80;
        tile[c8 * 84 + col] = x[((size_t)(b * NC + cib * 8 + c8) * NH + row) * NW + col];
    }
    __syncthreads();
    size_t base = (((size_t)(b * 32 + cib) * 82 + row + 1) * 82) * 8 + 8;
    for (int t = threadIdx.x; t < 320; t += 256) {
        int e = 2 * t, col = e >> 3, c8 = e & 7;
        bf16x2 pk = { (bf16)tile[c8 * 84 + col], (bf16)tile[(c8 + 1) * 84 + col] };
        *(bf16x2*)(xp + base + e) = pk;
    }
}

// ---------------- conv: implicit GEMM, 32co x 4rows x 80px per WG --------------
__global__ __launch_bounds__(256, 3) void conv_kernel(
    const bf16* __restrict__ xp, const bf16* __restrict__ wA,
    bf16* __restrict__ y, float* __restrict__ ssum, float* __restrict__ ssq)
{
    __shared__ bf16 Tt[15744];      // [6 rows][4 qq][82 cols][8 c8]
    __shared__ bf16 Aw[9216];       // [9 tap][4 qq][32 co][8 c8]
    __shared__ float wgs[4], wgq[4];

    int tid = threadIdx.x;
    int bid = blockIdx.x;
    int b = bid / 160; int rem = bid - b * 160;
    int ct = rem / 20; int rt = rem - ct * 20;
    int co0 = ct * 32, h0 = rt * 4;
    int wid = tid >> 6, lane = tid & 63;
    int n = lane & 15, q = lane >> 4;

    if (tid < 4) { wgs[tid] = 0.0f; wgq[tid] = 0.0f; }

    f32x4 acc[2][5];
    #pragma unroll
    for (int i = 0; i < 2; i++)
        #pragma unroll
        for (int j = 0; j < 5; j++) acc[i][j] = (f32x4){0.f, 0.f, 0.f, 0.f};

    const int aBase = q * 256 + n * 8;                    // + tap*1024 + mt*128
    const int bBase = wid * 2624 + q * 656 + n * 8;       // + r*2624 + s*8 + nt*128

    for (int c = 0; c < 8; c++) {
        __syncthreads();
        // stage input tile: 24 segments (tr,qq) x 82 uint4
        for (int e = tid; e < 1968; e += 256) {
            int seg = e / 82, u = e - seg * 82;
            int tr = seg >> 2, qq = seg & 3;
            *(uint4*)(Tt + seg * 656 + u * 8) =
                *(const uint4*)(xp + (((size_t)(b * 32 + c * 4 + qq) * 82 + (h0 + tr)) * 82 + u) * 8);
        }
        // stage weights: 36 segments (tap,qq) x 32 uint4
        for (int e = tid; e < 1152; e += 256) {
            int seg = e >> 5, u = e & 31;
            *(uint4*)(Aw + e * 8) =
                *(const uint4*)(wA + ((size_t)(c * 36 + seg) * 256 + co0 + u) * 8);
        }
        __syncthreads();

        #pragma unroll
        for (int tap = 0; tap < 9; tap++) {
            const int r = tap / 3, s = tap - 3 * (tap / 3);
            bf16x8 af[2], bfr[5];
            #pragma unroll
            for (int mt = 0; mt < 2; mt++)
                af[mt] = *(const bf16x8*)(Aw + tap * 1024 + aBase + mt * 128);
            #pragma unroll
            for (int nt = 0; nt < 5; nt++)
                bfr[nt] = *(const bf16x8*)(Tt + bBase + r * 2624 + s * 8 + nt * 128);
            #pragma unroll
            for (int mt = 0; mt < 2; mt++)
                #pragma unroll
                for (int nt = 0; nt < 5; nt++)
                    acc[mt][nt] = __builtin_amdgcn_mfma_f32_16x16x32_bf16(
                        af[mt], bfr[nt], acc[mt][nt], 0, 0, 0);
        }
    }

    // epilogue: bf16 store (chunked layout) + group stats
    int h = h0 + wid;
    #pragma unroll
    for (int mt = 0; mt < 2; mt++) {
        float s1 = 0.0f, s2 = 0.0f;
        int co = co0 + mt * 16 + q * 4;
        int cib = co >> 3, c8 = co & 7;
        #pragma unroll
        for (int nt = 0; nt < 5; nt++) {
            int col = nt * 16 + n;
            bf16x4 pk;
            #pragma unroll
            for (int rg = 0; rg < 4; rg++) {
                float v = acc[mt][nt][rg];
                pk[rg] = (bf16)v;
                s1 += v;
                s2 = fmaf(v, v, s2);
            }
            *(bf16x4*)(y + ((((size_t)(b * 32 + cib) * 80 + h) * 80 + col) * 8 + c8)) = pk;
        }
        #pragma unroll
        for (int off = 1; off < 16; off <<= 1) {
            s1 += __shfl_xor(s1, off, 64);
            s2 += __shfl_xor(s2, off, 64);
        }
        if (n == 0) {
            int gl = mt * 2 + (q >> 1);
            atomicAdd(&wgs[gl], s1);
            atomicAdd(&wgq[gl], s2);
        }
    }
    __syncthreads();
    if (tid < 4) {
        atomicAdd(&ssum[b * 32 + ct * 4 + tid], wgs[tid]);
        atomicAdd(&ssq [b * 32 + ct * 4 + tid], wgq[tid]);
    }
}

// ---------------- finalize stats ----------------
__global__ void statfin_kernel(const float* __restrict__ s, const float* __restrict__ sq,
                               float* __restrict__ mu, float* __restrict__ rs)
{
    int i = threadIdx.x;
    const float cnt = (float)(8 * NHW);
    float m = s[i] / cnt;
    float v = sq[i] / cnt - m * m;
    mu[i] = m;
    rs[i] = rsqrtf(v + GN_EPS);
}

// ---------------- prep2: y1 -> GN1+ReLU -> xp interior --------------------------
__global__ __launch_bounds__(256) void prep2_kernel(
    const bf16* __restrict__ y, bf16* __restrict__ xp,
    const float* __restrict__ mu, const float* __restrict__ rs,
    const float* __restrict__ gamma, const float* __restrict__ beta)
{
    int bid = blockIdx.x;
    int b = bid / 640; int rem = bid - b * 640;
    int cib = rem / 20; int rq = rem - cib * 20;
    int gidx = b * 32 + cib;
    float m = mu[gidx], r = rs[gidx];
    const bf16* src = y + (size_t)(b * 32 + cib) * 51200 + rq * 2560;
    for (int u = threadIdx.x; u < 1280; u += 256) {
        int e = 2 * u;
        int row = rq * 4 + e / 640;
        int w640 = e % 640;
        int c8 = e & 7;
        int c = cib * 8 + c8;
        float sc0 = r * gamma[c],     sh0 = beta[c]     - m * sc0;
        float sc1 = r * gamma[c + 1], sh1 = beta[c + 1] - m * sc1;
        bf16x2 iv = *(const bf16x2*)(src + e);
        bf16x2 pk = { (bf16)fmaxf(fmaf((float)iv[0], sc0, sh0), 0.0f),
                      (bf16)fmaxf(fmaf((float)iv[1], sc1, sh1), 0.0f) };
        size_t xidx = (((size_t)(b * 32 + cib) * 82 + row + 1) * 82) * 8 + 8 + w640;
        *(bf16x2*)(xp + xidx) = pk;
    }
}

// ---------------- final: out = relu(gn2(y2) * gate + x), NCHW f32 ---------------
__global__ __launch_bounds__(256) void final_kernel(
    const bf16* __restrict__ y, const float* __restrict__ x,
    const float* __restrict__ gate,
    const float* __restrict__ mu, const float* __restrict__ rs,
    const float* __restrict__ gamma, const float* __restrict__ beta,
    float* __restrict__ out)
{
    __shared__ float lds[8 * 324];
    int bid = blockIdx.x;
    int b = bid / 640; int rem = bid - b * 640;
    int cib = rem / 20; int rq = rem - cib * 20;
    int gidx = b * 32 + cib;
    float m = mu[gidx], r = rs[gidx];
    const bf16* src = y + (size_t)(b * 32 + cib) * 51200 + rq * 2560;
    for (int u = threadIdx.x; u < 1280; u += 256) {
        int e = 2 * u;
        int c8 = e & 7;
        int rc = e >> 3;
        int c = cib * 8 + c8;
        float sc0 = r * gamma[c],     sh0 = beta[c]     - m * sc0;
        float sc1 = r * gamma[c + 1], sh1 = beta[c + 1] - m * sc1;
        bf16x2 iv = *(const bf16x2*)(src + e);
        lds[c8 * 324 + rc]       = fmaf((float)iv[0], sc0, sh0);
        lds[(c8 + 1) * 324 + rc] = fmaf((float)iv[1], sc1, sh1);
    }
    __syncthreads();
    const float* gp = gate + b * NHW + rq * 320;
    for (int e2 = threadIdx.x; e2 < 2560; e2 += 256) {
        int c8 = e2 / 320, rc = e2 - c8 * 320;
        int c = cib * 8 + c8;
        size_t oidx = (size_t)(b * NC + c) * NHW + rq * 320 + rc;
        float v = fmaf(lds[c8 * 324 + rc], gp[rc], x[oidx]);
        out[oidx] = fmaxf(v, 0.0f);
    }
}

extern "C" void kernel_launch(void* const* d_in, const int* in_sizes, int n_in,
                              void* d_out, int out_size, void* d_ws, size_t ws_size,
                              hipStream_t stream)
{
    const float* x     = (const float*)d_in[0];
    const float* w1    = (const float*)d_in[1];
    const float* gn1_w = (const float*)d_in[2];
    const float* gn1_b = (const float*)d_in[3];
    const float* w2    = (const float*)d_in[4];
    const float* gn2_w = (const float*)d_in[5];
    const float* gn2_b = (const float*)d_in[6];
    const float* gw    = (const float*)d_in[7];
    const float* gb    = (const float*)d_in[8];

    // xp padded-chunked scratch lives in d_out (27.5 MB < 52.4 MB); final pass
    // rewrites all of d_out last.
    bf16*  xp  = (bf16*)d_out;
    float* out = (float*)d_out;

    // ws layout (28.8 MB total)
    char* wsb = (char*)d_ws;
    bf16*  y     = (bf16*)wsb;                                   // 26,214,400 B
    float* gate  = (float*)(wsb + 26214400);                     //    204,800 B
    bf16*  wA1   = (bf16*)(wsb + 26214400 + 204800);             //  1,179,648 B
    bf16*  wA2   = wA1 + 589824;                                 //  1,179,648 B
    float* stats = (float*)(wsb + 26214400 + 204800 + 2 * 1179648);
    float* s1  = stats,        * s1q = stats + 256;
    float* mu1 = stats + 512,  * rs1 = stats + 768;
    float* s2  = stats + 1024, * s2q = stats + 1280;
    float* mu2 = stats + 1536, * rs2 = stats + 1792;

    zero_xp_kernel<<<6724, 256, 0, stream>>>((uint4*)d_out);
    zero_stats_kernel<<<1, 256, 0, stream>>>(stats);
    repack_w_kernel<<<2304, 256, 0, stream>>>(w1, wA1);
    repack_w_kernel<<<2304, 256, 0, stream>>>(w2, wA2);
    gate_kernel<<<800, 256, 0, stream>>>(x, gw, gb, gate);
    prep1_kernel<<<20480, 256, 0, stream>>>(x, xp);
    conv_kernel<<<1280, 256, 0, stream>>>(xp, wA1, y, s1, s1q);
    statfin_kernel<<<1, 256, 0, stream>>>(s1, s1q, mu1, rs1);
    prep2_kernel<<<5120, 256, 0, stream>>>(y, xp, mu1, rs1, gn1_w, gn1_b);
    conv_kernel<<<1280, 256, 0, stream>>>(xp, wA2, y, s2, s2q);
    statfin_kernel<<<1, 256, 0, stream>>>(s2, s2q, mu2, rs2);
    final_kernel<<<5120, 256, 0, stream>>>(y, x, gate, mu2, rs2, gn2_w, gn2_b, out);
}

// Round 3
// 320.290 us; speedup vs baseline: 9.3170x; 1.1624x over previous
//
#include <hip/hip_runtime.h>
#include <math.h>

#define NB   8
#define NC   256
#define NH   80
#define NW   80
#define NHW  6400
#define GN_EPS 1e-5f

typedef __bf16 bf16;
typedef bf16 bf16x2 __attribute__((ext_vector_type(2)));
typedef bf16 bf16x4 __attribute__((ext_vector_type(4)));
typedef bf16 bf16x8 __attribute__((ext_vector_type(8)));
typedef float f32x4 __attribute__((ext_vector_type(4)));

typedef __attribute__((address_space(1))) void gvoid;
typedef __attribute__((address_space(3))) void lvoid;
__device__ __forceinline__ void glds16(const void* g, void* l) {
    __builtin_amdgcn_global_load_lds((const gvoid*)g, (lvoid*)l, 16, 0, 0);
}

// Tt: [4 qq][stride 4616 elems]  rows 0..6 at row*656, col*8, c8
#define TT_Q 4616
// Aw: [9 tap][4 qq] qq stride 520 elems (1040 B -> bank offset +4)
#define AW_Q 520
#define AW_T 2080

// ---------------- setup: zero gate-acc + stats, repack both weight tensors ------
// wA layout: [chunk(8)][tap(9)][qq(4)][co(256)][c8(8)] bf16
__global__ __launch_bounds__(256) void setup_kernel(
    const float* __restrict__ w1, const float* __restrict__ w2,
    bf16* __restrict__ wA1, bf16* __restrict__ wA2,
    float* __restrict__ gacc, float* __restrict__ stats)
{
    int blk = blockIdx.x, tid = threadIdx.x;
    if (blk < 200) { gacc[blk * 256 + tid] = 0.0f; return; }
    if (blk == 200) {
        #pragma unroll
        for (int k = 0; k < 8; k++) stats[tid + k * 256] = 0.0f;
        return;
    }
    int rb = blk - 201;                          // 0..4607
    const float* w = (rb < 2304) ? w1 : w2;
    bf16* wA       = (rb < 2304) ? wA1 : wA2;
    int idx = (rb % 2304) * 256 + tid;
    int c8 = idx & 7;
    int co = (idx >> 3) & 255;
    int qq = (idx >> 11) & 3;
    int tc = idx >> 13;                          // 0..71
    int tap = tc % 9, chunk = tc / 9;
    int ci = chunk * 32 + qq * 8 + c8;
    wA[idx] = (bf16)w[(size_t)(co * 256 + ci) * 9 + tap];
}

// ---------------- prep1: x NCHW f32 -> xp[b][cib][82][82][8] bf16 + halo + gate dot
__global__ __launch_bounds__(256) void prep1_kernel(
    const float* __restrict__ x, bf16* __restrict__ xp,
    const float* __restrict__ gw, float* __restrict__ gacc)
{
    __shared__ float tile[8 * 84];
    int bid = blockIdx.x;
    int row = bid % 80;
    int cib = (bid / 80) & 31;
    int b   = bid / 2560;
    for (int e = threadIdx.x; e < 640; e += 256) {
        int c8 = e / 80, col = e - c8 * 80;
        tile[c8 * 84 + col] = x[((size_t)(b * NC + cib * 8 + c8) * NH + row) * NW + col];
    }
    __syncthreads();
    // interior pack
    size_t base = (((size_t)(b * 32 + cib) * 82 + row + 1) * 82) * 8 + 8;
    for (int t = threadIdx.x; t < 320; t += 256) {
        int e = 2 * t, col = e >> 3, c8 = e & 7;
        bf16x2 pk = { (bf16)tile[c8 * 84 + col], (bf16)tile[(c8 + 1) * 84 + col] };
        *(bf16x2*)(xp + base + e) = pk;
    }
    // gate partial: sum over this block's 8 channels
    if (threadIdx.x < 80) {
        int col = threadIdx.x;
        float s = 0.0f;
        #pragma unroll
        for (int c8 = 0; c8 < 8; c8++) s = fmaf(tile[c8 * 84 + col], gw[cib * 8 + c8], s);
        atomicAdd(gacc + (size_t)b * NHW + row * 80 + col, s);
    }
    // halo zeroing
    const uint4 z4 = make_uint4(0u, 0u, 0u, 0u);
    size_t img = ((size_t)(b * 32 + cib)) * 82;
    if (threadIdx.x < 2) {
        int col = threadIdx.x * 81;
        *(uint4*)(xp + ((img + row + 1) * 82 + col) * 8) = z4;
    }
    if (row == 0 || row == 79) {
        int prow = (row == 0) ? 0 : 81;
        for (int u = threadIdx.x; u < 82; u += 256)
            *(uint4*)(xp + ((img + prow) * 82 + u) * 8) = z4;
    }
}

// ---------------- gate finalize: g = relu(tanh(acc + b)) in place ----------------
__global__ __launch_bounds__(256) void gate_fin_kernel(
    float* __restrict__ gacc, const float* __restrict__ gb)
{
    int i = blockIdx.x * 256 + threadIdx.x;
    gacc[i] = fmaxf(tanhf(gacc[i] + gb[0]), 0.0f);
}

// ---------------- conv: implicit GEMM, block = 64co x 5rows x 80px, 5 waves -----
__global__ __launch_bounds__(320, 3) void conv_kernel(
    const bf16* __restrict__ xp, const bf16* __restrict__ wA,
    bf16* __restrict__ y, float* __restrict__ ssum, float* __restrict__ ssq)
{
    __shared__ __align__(16) bf16 Tt[4 * TT_Q];   // 36928 B
    __shared__ __align__(16) bf16 Aw[9 * AW_T];   // 37440 B
    __shared__ float wgs[8], wgq[8];

    int tid  = threadIdx.x;
    int wid  = tid >> 6;            // 0..4 (wave = one output row)
    int lane = tid & 63;
    int n = lane & 15, q = lane >> 4;

    int bid = blockIdx.x;           // 8b * 4ct * 16rt = 512
    int b   = bid >> 6;
    int rem = bid & 63;
    int ct  = rem >> 4;
    int rt  = rem & 15;
    int co0 = ct * 64, h0 = rt * 5;

    if (tid < 8) { wgs[tid] = 0.0f; wgq[tid] = 0.0f; }

    f32x4 acc[4][5];
    #pragma unroll
    for (int i = 0; i < 4; i++)
        #pragma unroll
        for (int j = 0; j < 5; j++) acc[i][j] = (f32x4){0.f, 0.f, 0.f, 0.f};

    for (int c = 0; c < 8; c++) {
        __syncthreads();
        // Tt: waves 0..3 stage qq=wid: 7 rows = 9184 B contiguous (9216 B copied,
        // last 32 B land in intra-section pad, never read)
        if (wid < 4) {
            const char* s8 = (const char*)(xp +
                (((size_t)(b * 32 + c * 4 + wid) * 82 + h0) * 82) * 8);
            char* l8 = (char*)(Tt + wid * TT_Q);
            #pragma unroll
            for (int u = 0; u < 9; u++)
                glds16(s8 + u * 1024 + lane * 16, l8 + u * 1024);
        }
        // Aw: 36 (tap,qq) pairs spread over 5 waves, 1 KB each
        for (int p = wid; p < 36; p += 5) {
            int tap = p >> 2, qq = p & 3;
            const char* s8 = (const char*)(wA + ((size_t)(c * 36 + p) * 256 + co0) * 8);
            char* l8 = (char*)(Aw + tap * AW_T + qq * AW_Q);
            glds16(s8 + lane * 16, l8);
        }
        __syncthreads();

        #pragma unroll
        for (int tap = 0; tap < 9; tap++) {
            const int r = tap / 3, s = tap - 3 * r;
            bf16x8 af[4], bfr[5];
            #pragma unroll
            for (int mt = 0; mt < 4; mt++)
                af[mt] = *(const bf16x8*)(Aw + tap * AW_T + q * AW_Q + (mt * 16 + n) * 8);
            #pragma unroll
            for (int nt = 0; nt < 5; nt++)
                bfr[nt] = *(const bf16x8*)(Tt + q * TT_Q + (wid + r) * 656 + (s + nt * 16 + n) * 8);
            #pragma unroll
            for (int mt = 0; mt < 4; mt++)
                #pragma unroll
                for (int nt = 0; nt < 5; nt++)
                    acc[mt][nt] = __builtin_amdgcn_mfma_f32_16x16x32_bf16(
                        af[mt], bfr[nt], acc[mt][nt], 0, 0, 0);
        }
    }

    // epilogue: store y (chunked bf16) + group stats
    int h = h0 + wid;
    #pragma unroll
    for (int mt = 0; mt < 4; mt++) {
        float s1 = 0.0f, s2 = 0.0f;
        int co  = co0 + mt * 16 + q * 4;
        int cib = co >> 3, c8 = co & 7;
        #pragma unroll
        for (int nt = 0; nt < 5; nt++) {
            int col = nt * 16 + n;
            bf16x4 pk;
            #pragma unroll
            for (int rg = 0; rg < 4; rg++) {
                float v = acc[mt][nt][rg];
                pk[rg] = (bf16)v;
                s1 += v;
                s2 = fmaf(v, v, s2);
            }
            *(bf16x4*)(y + ((((size_t)(b * 32 + cib) * 80 + h) * 80 + col) * 8 + c8)) = pk;
        }
        #pragma unroll
        for (int off = 1; off < 16; off <<= 1) {
            s1 += __shfl_xor(s1, off, 64);
            s2 += __shfl_xor(s2, off, 64);
        }
        if (n == 0) {
            int gl = mt * 2 + (q >> 1);
            atomicAdd(&wgs[gl], s1);
            atomicAdd(&wgq[gl], s2);
        }
    }
    __syncthreads();
    if (tid < 8) {
        atomicAdd(&ssum[b * 32 + ct * 8 + tid], wgs[tid]);
        atomicAdd(&ssq [b * 32 + ct * 8 + tid], wgq[tid]);
    }
}

// ---------------- finalize stats ----------------
__global__ void statfin_kernel(const float* __restrict__ s, const float* __restrict__ sq,
                               float* __restrict__ mu, float* __restrict__ rs)
{
    int i = threadIdx.x;
    const float cnt = (float)(8 * NHW);
    float m = s[i] / cnt;
    float v = sq[i] / cnt - m * m;
    mu[i] = m;
    rs[i] = rsqrtf(v + GN_EPS);
}

// ---------------- prep2: y1 -> GN1+ReLU -> xp interior --------------------------
__global__ __launch_bounds__(256) void prep2_kernel(
    const bf16* __restrict__ y, bf16* __restrict__ xp,
    const float* __restrict__ mu, const float* __restrict__ rs,
    const float* __restrict__ gamma, const float* __restrict__ beta)
{
    int bid = blockIdx.x;
    int b = bid / 640; int rem = bid - b * 640;
    int cib = rem / 20; int rq = rem - cib * 20;
    int gidx = b * 32 + cib;
    float m = mu[gidx], r = rs[gidx];
    const bf16* src = y + (size_t)(b * 32 + cib) * 51200 + rq * 2560;
    for (int u = threadIdx.x; u < 1280; u += 256) {
        int e = 2 * u;
        int row = rq * 4 + e / 640;
        int w640 = e % 640;
        int c8 = e & 7;
        int c = cib * 8 + c8;
        float sc0 = r * gamma[c],     sh0 = beta[c]     - m * sc0;
        float sc1 = r * gamma[c + 1], sh1 = beta[c + 1] - m * sc1;
        bf16x2 iv = *(const bf16x2*)(src + e);
        bf16x2 pk = { (bf16)fmaxf(fmaf((float)iv[0], sc0, sh0), 0.0f),
                      (bf16)fmaxf(fmaf((float)iv[1], sc1, sh1), 0.0f) };
        size_t xidx = (((size_t)(b * 32 + cib) * 82 + row + 1) * 82) * 8 + 8 + w640;
        *(bf16x2*)(xp + xidx) = pk;
    }
}

// ---------------- final: out = relu(gn2(y2) * gate + x), NCHW f32 ---------------
__global__ __launch_bounds__(256) void final_kernel(
    const bf16* __restrict__ y, const float* __restrict__ x,
    const float* __restrict__ gate,
    const float* __restrict__ mu, const float* __restrict__ rs,
    const float* __restrict__ gamma, const float* __restrict__ beta,
    float* __restrict__ out)
{
    __shared__ float lds[8 * 324];
    int bid = blockIdx.x;
    int b = bid / 640; int rem = bid - b * 640;
    int cib = rem / 20; int rq = rem - cib * 20;
    int gidx = b * 32 + cib;
    float m = mu[gidx], r = rs[gidx];
    const bf16* src = y + (size_t)(b * 32 + cib) * 51200 + rq * 2560;
    for (int u = threadIdx.x; u < 1280; u += 256) {
        int e = 2 * u;
        int c8 = e & 7;
        int rc = e >> 3;
        int c = cib * 8 + c8;
        float sc0 = r * gamma[c],     sh0 = beta[c]     - m * sc0;
        float sc1 = r * gamma[c + 1], sh1 = beta[c + 1] - m * sc1;
        bf16x2 iv = *(const bf16x2*)(src + e);
        lds[c8 * 324 + rc]       = fmaf((float)iv[0], sc0, sh0);
        lds[(c8 + 1) * 324 + rc] = fmaf((float)iv[1], sc1, sh1);
    }
    __syncthreads();
    const float* gp = gate + b * NHW + rq * 320;
    for (int e2 = threadIdx.x; e2 < 2560; e2 += 256) {
        int c8 = e2 / 320, rc = e2 - c8 * 320;
        int c = cib * 8 + c8;
        size_t oidx = (size_t)(b * NC + c) * NHW + rq * 320 + rc;
        float v = fmaf(lds[c8 * 324 + rc], gp[rc], x[oidx]);
        out[oidx] = fmaxf(v, 0.0f);
    }
}

extern "C" void kernel_launch(void* const* d_in, const int* in_sizes, int n_in,
                              void* d_out, int out_size, void* d_ws, size_t ws_size,
                              hipStream_t stream)
{
    const float* x     = (const float*)d_in[0];
    const float* w1    = (const float*)d_in[1];
    const float* gn1_w = (const float*)d_in[2];
    const float* gn1_b = (const float*)d_in[3];
    const float* w2    = (const float*)d_in[4];
    const float* gn2_w = (const float*)d_in[5];
    const float* gn2_b = (const float*)d_in[6];
    const float* gw    = (const float*)d_in[7];
    const float* gb    = (const float*)d_in[8];

    bf16*  xp  = (bf16*)d_out;      // 27.5 MB scratch inside d_out (52.4 MB)
    float* out = (float*)d_out;

    char* wsb = (char*)d_ws;
    bf16*  y     = (bf16*)wsb;                                   // 26,214,400 B
    float* gacc  = (float*)(wsb + 26214400);                     //    204,800 B
    bf16*  wA1   = (bf16*)(wsb + 26214400 + 204800);             //  1,179,648 B
    bf16*  wA2   = wA1 + 589824;                                 //  1,179,648 B
    float* stats = (float*)(wsb + 26214400 + 204800 + 2 * 1179648);
    float* s1  = stats,        * s1q = stats + 256;
    float* mu1 = stats + 512,  * rs1 = stats + 768;
    float* s2  = stats + 1024, * s2q = stats + 1280;
    float* mu2 = stats + 1536, * rs2 = stats + 1792;

    setup_kernel<<<4809, 256, 0, stream>>>(w1, w2, wA1, wA2, gacc, stats);
    prep1_kernel<<<20480, 256, 0, stream>>>(x, xp, gw, gacc);
    gate_fin_kernel<<<200, 256, 0, stream>>>(gacc, gb);
    conv_kernel<<<512, 320, 0, stream>>>(xp, wA1, y, s1, s1q);
    statfin_kernel<<<1, 256, 0, stream>>>(s1, s1q, mu1, rs1);
    prep2_kernel<<<5120, 256, 0, stream>>>(y, xp, mu1, rs1, gn1_w, gn1_b);
    conv_kernel<<<512, 320, 0, stream>>>(xp, wA2, y, s2, s2q);
    statfin_kernel<<<1, 256, 0, stream>>>(s2, s2q, mu2, rs2);
    final_kernel<<<5120, 256, 0, stream>>>(y, x, gacc, mu2, rs2, gn2_w, gn2_b, out);
}